// Round 8
// baseline (717.936 us; speedup 1.0000x reference)
//
#include <hip/hip_runtime.h>
#include <hip/hip_bf16.h>
#include <cstdint>

#define BN_EPS 1e-5f

typedef __attribute__((ext_vector_type(8))) short bf16x8;
typedef __attribute__((ext_vector_type(4))) float f32x4;
typedef __attribute__((ext_vector_type(2))) float f32x2;
typedef unsigned int uint32;

__device__ inline unsigned short f2bf(float f) {
  unsigned int b = __float_as_uint(f);
  b += 0x7FFFu + ((b >> 16) & 1u);  // RNE
  return (unsigned short)(b >> 16);
}
__device__ inline float bf2f(unsigned short u) { return __uint_as_float((unsigned int)u << 16); }
__device__ inline unsigned char f2fp8(float f) {
  int p = __builtin_amdgcn_cvt_pk_fp8_f32(f, f, 0, false);  // OCP e4m3 on gfx950
  return (unsigned char)(p & 0xFF);
}

// decode 8 fp4(e2m1) nibbles (dword q) -> 8 floats (unit scale), order v[0..7]=nibble 0..7
__device__ inline void dec8(uint32 q, float* v) {
  const uint32 lutLO = 0x3C383000u;  // fp8 bytes for mags {0,0.5,1,1.5}
  const uint32 lutHI = 0x4C484440u;  // fp8 bytes for mags {2,3,4,6}
  uint32 b0 = q & 0x0f0f0f0fu;          // nibbles 0,2,4,6
  uint32 b1 = (q >> 4) & 0x0f0f0f0fu;   // nibbles 1,3,5,7
  uint32 f0 = __builtin_amdgcn_perm(lutHI, lutLO, b0 & 0x07070707u) | ((b0 & 0x08080808u) << 4);
  uint32 f1 = __builtin_amdgcn_perm(lutHI, lutLO, b1 & 0x07070707u) | ((b1 & 0x08080808u) << 4);
  f32x2 a;
  a = __builtin_amdgcn_cvt_pk_f32_fp8((int)f0, false); v[0] = a.x; v[2] = a.y;
  a = __builtin_amdgcn_cvt_pk_f32_fp8((int)f0, true);  v[4] = a.x; v[6] = a.y;
  a = __builtin_amdgcn_cvt_pk_f32_fp8((int)f1, false); v[1] = a.x; v[3] = a.y;
  a = __builtin_amdgcn_cvt_pk_f32_fp8((int)f1, true);  v[5] = a.x; v[7] = a.y;
}

// ---------------- pack weights: bf16, transposed [Ncols][K] ----------------
__global__ void pack_b1t(const float* __restrict__ W1, const float* __restrict__ root1,
                         const float* __restrict__ Wskip, __hip_bfloat16* __restrict__ B1t) {
  int idx = blockIdx.x * blockDim.x + threadIdx.x;
  if (idx >= 640 * 32) return;
  int n = idx >> 5, k = idx & 31;
  float v;
  if (n < 512) v = W1[(n & 7) * (32 * 64) + k * 64 + (n >> 3)];
  else if (n < 576) v = root1[k * 64 + (n - 512)];
  else v = Wskip[k * 64 + (n - 576)];
  ((unsigned short*)B1t)[idx] = f2bf(v);
}

__global__ void pack_b2t(const float* __restrict__ W2, const float* __restrict__ root2,
                         __hip_bfloat16* __restrict__ B2t) {
  int idx = blockIdx.x * blockDim.x + threadIdx.x;
  if (idx >= 576 * 64) return;
  int n = idx >> 6, k = idx & 63;
  float v;
  if (n < 512) v = W2[(n & 7) * (64 * 64) + k * 64 + (n >> 3)];
  else v = root2[k * 64 + (n - 512)];
  ((unsigned short*)B2t)[idx] = f2bf(v);
}

// ---------------- dst-CSR build ----------------
__global__ void hist_dst(const int* __restrict__ ei, int E, int* __restrict__ indeg) {
  int e = blockIdx.x * 256 + threadIdx.x;
  if (e >= E) return;
  atomicAdd(&indeg[ei[E + e]], 1);
}

__global__ __launch_bounds__(1024) void scan_block(const int* __restrict__ in,
                                                   int* __restrict__ part,
                                                   int* __restrict__ bsum, int N) {
  __shared__ int tmp[1024];
  int i = blockIdx.x * 1024 + threadIdx.x;
  int v = (i < N) ? in[i] : 0;
  tmp[threadIdx.x] = v;
  __syncthreads();
  for (int ofs = 1; ofs < 1024; ofs <<= 1) {
    int t = (threadIdx.x >= (unsigned)ofs) ? tmp[threadIdx.x - ofs] : 0;
    __syncthreads();
    tmp[threadIdx.x] += t;
    __syncthreads();
  }
  if (i < N) part[i] = tmp[threadIdx.x] - v;
  if (threadIdx.x == 1023) bsum[blockIdx.x] = tmp[1023];
}

__global__ __launch_bounds__(1024) void scan_top(int* __restrict__ bsum, int nb) {
  __shared__ int tmp[1024];
  int v = (threadIdx.x < (unsigned)nb) ? bsum[threadIdx.x] : 0;
  tmp[threadIdx.x] = v;
  __syncthreads();
  for (int ofs = 1; ofs < 1024; ofs <<= 1) {
    int t = (threadIdx.x >= (unsigned)ofs) ? tmp[threadIdx.x - ofs] : 0;
    __syncthreads();
    tmp[threadIdx.x] += t;
    __syncthreads();
  }
  if (threadIdx.x < (unsigned)nb) bsum[threadIdx.x] = tmp[threadIdx.x] - v;
}

__global__ void scan_add(const int* __restrict__ part, const int* __restrict__ bsum,
                         int* __restrict__ rowptr, int* __restrict__ cursor, int N, int E) {
  int i = blockIdx.x * 256 + threadIdx.x;
  if (i < N) {
    int r = part[i] + bsum[i >> 10];
    rowptr[i] = r;
    cursor[i] = r;
  }
  if (i == 0) rowptr[N] = E;
}

// Scatter: per edge (dst-grouped pos) store src + 8 basis weights as fp16 (16 B).
__global__ void edge_scatter(const int* __restrict__ ei, const float* __restrict__ attr, int E,
                             int* __restrict__ cursor, int* __restrict__ wsrc,
                             uint4* __restrict__ wts) {
  int e = blockIdx.x * 256 + threadIdx.x;
  if (e >= E) return;
  int src = ei[e], dst = ei[E + e];
  float u0 = attr[3 * e + 0], u1 = attr[3 * e + 1], u2 = attr[3 * e + 2];
  float p0 = 1.f - u0, p1 = 1.f - u1, p2 = 1.f - u2;
  float w00 = p1 * p2, w10 = u1 * p2, w01 = p1 * u2, w11 = u1 * u2;
  float w[8] = {p0 * w00, u0 * w00, p0 * w10, u0 * w10,
                p0 * w01, u0 * w01, p0 * w11, u0 * w11};
  union { _Float16 h[8]; uint4 u; } pk;
#pragma unroll
  for (int j = 0; j < 8; j++) pk.h[j] = (_Float16)w[j];
  int pos = atomicAdd(&cursor[dst], 1);
  wsrc[pos] = src;
  wts[pos] = pk.u;
}

// ---------------- MFMA GEMM: [Yq fp8 (cols 0..511) | RS bf16 (cols 512+)] = A @ Bt^T ----------
// AF32: A is fp32 (layer 1) or bf16 (layer 2). BN applies scale/shift+ELU to A.
template <int K, bool BN, bool AF32>
__global__ __launch_bounds__(256) void gemm_mfma(const void* __restrict__ Av,
                                                 const __hip_bfloat16* __restrict__ Bt,
                                                 unsigned char* __restrict__ Yq,
                                                 __hip_bfloat16* __restrict__ RS, int M,
                                                 int Ncols, int rss,
                                                 const float* __restrict__ scale,
                                                 const float* __restrict__ shift) {
  const int tid = threadIdx.x;
  const int lane = tid & 63;
  const int wv = tid >> 6;
  const int rowbase = blockIdx.x * 64 + wv * 16;
  const int m = lane & 15;
  const int quad = lane >> 4;
  const int k0 = quad * 8;

  int ar = rowbase + m;
  if (ar > M - 1) ar = M - 1;

  bf16x8 afrag[K / 32];
#pragma unroll
  for (int f = 0; f < K / 32; f++) {
    float v[8];
#pragma unroll
    for (int j = 0; j < 8; j++) {
      if (AF32) v[j] = ((const float*)Av)[(size_t)ar * K + f * 32 + k0 + j];
      else v[j] = bf2f(((const unsigned short*)Av)[(size_t)ar * K + f * 32 + k0 + j]);
    }
    if (BN) {
#pragma unroll
      for (int j = 0; j < 8; j++) {
        float t = v[j] * scale[f * 32 + k0 + j] + shift[f * 32 + k0 + j];
        v[j] = t > 0.f ? t : expm1f(t);
      }
    }
    bf16x8 af;
#pragma unroll
    for (int j = 0; j < 8; j++) af[j] = (short)f2bf(v[j]);
    afrag[f] = af;
  }

  for (int col0 = 0; col0 < Ncols; col0 += 16) {
    f32x4 acc = {0.f, 0.f, 0.f, 0.f};
#pragma unroll
    for (int f = 0; f < K / 32; f++) {
      const __hip_bfloat16* bp = Bt + (size_t)(col0 + m) * K + f * 32 + k0;
      bf16x8 bfrag = *(const bf16x8*)bp;
      acc = __builtin_amdgcn_mfma_f32_16x16x32_bf16(afrag[f], bfrag, acc, 0, 0, 0);
    }
    const int col = col0 + m;
#pragma unroll
    for (int r = 0; r < 4; r++) {
      int gr = rowbase + quad * 4 + r;
      if (gr < M) {
        if (col < 512) Yq[(size_t)gr * 512 + col] = f2fp8(acc[r]);
        else ((unsigned short*)RS)[(size_t)gr * rss + (col - 512)] = f2bf(acc[r]);
      }
    }
  }
}

// ---------------- quant4: fp8 table row -> fp4(e2m1) + per-64ch fp32 scale ----------------
__global__ __launch_bounds__(256) void quant4(const unsigned char* __restrict__ Yq, int N,
                                              uint32* __restrict__ Q4, float* __restrict__ S) {
  int row = blockIdx.x * 4 + (threadIdx.x >> 6);
  if (row >= N) return;
  int lane = threadIdx.x & 63;
  uint2 q8 = *(const uint2*)(Yq + (size_t)row * 512 + lane * 8);
  float v[8];
  f32x2 a;
  a = __builtin_amdgcn_cvt_pk_f32_fp8((int)q8.x, false); v[0] = a.x; v[1] = a.y;
  a = __builtin_amdgcn_cvt_pk_f32_fp8((int)q8.x, true);  v[2] = a.x; v[3] = a.y;
  a = __builtin_amdgcn_cvt_pk_f32_fp8((int)q8.y, false); v[4] = a.x; v[5] = a.y;
  a = __builtin_amdgcn_cvt_pk_f32_fp8((int)q8.y, true);  v[6] = a.x; v[7] = a.y;
  float mx = 0.f;
#pragma unroll
  for (int j = 0; j < 8; j++) mx = fmaxf(mx, fabsf(v[j]));
  mx = fmaxf(mx, __shfl_xor(mx, 1, 64));
  mx = fmaxf(mx, __shfl_xor(mx, 2, 64));
  mx = fmaxf(mx, __shfl_xor(mx, 4, 64));  // max over 8-lane group = 64 channels
  float sc = mx * (1.f / 6.f);
  float inv = mx > 0.f ? 6.f / mx : 0.f;
  uint32 nibs = 0;
#pragma unroll
  for (int j = 0; j < 8; j++) {
    float av = fabsf(v[j]) * inv;  // in [0,6]
    uint32 n = av < 0.25f ? 0u : av < 0.75f ? 1u : av < 1.25f ? 2u : av < 1.75f ? 3u
               : av < 2.5f ? 4u : av < 3.5f ? 5u : av < 5.f ? 6u : 7u;
    if (v[j] < 0.f) n |= 8u;
    nibs |= n << (4 * j);
  }
  Q4[(size_t)row * 64 + lane] = nibs;
  if ((lane & 7) == 0) S[row * 8 + (lane >> 3)] = sc;
}

// ---------------- dst-grouped message + finish: one wave per dst node ----------------
// L1: gather fp4 Q4 (+per-64ch scale), write hout bf16 + sout(out) + 4 stats.
// L2: gather fp8 Yq, write hout bf16 + 2 stats.
template <bool L1>
__global__ __launch_bounds__(256) void msg_dst(const unsigned char* __restrict__ Yq,
                                               const uint32* __restrict__ Q4,
                                               const float* __restrict__ S,
                                               const __hip_bfloat16* __restrict__ RS,
                                               const int* __restrict__ rowptr,
                                               const int* __restrict__ wsrc,
                                               const uint4* __restrict__ wts, int N,
                                               __hip_bfloat16* __restrict__ hout,
                                               float* __restrict__ sout,
                                               double* __restrict__ sums) {
  const int tid = threadIdx.x;
  const int lane = tid & 63;
  const int wv = tid >> 6;
  const int nwaves = gridDim.x * 4;
  const int RSS = L1 ? 128 : 64;
  float sh = 0.f, sh2 = 0.f, ss = 0.f, ss2 = 0.f;

  for (int n = blockIdx.x * 4 + wv; n < N; n += nwaves) {
    const int e0 = __builtin_amdgcn_readfirstlane(rowptr[n]);
    const int e1 = __builtin_amdgcn_readfirstlane(rowptr[n + 1]);
    float acc0 = 0.f, acc1 = 0.f;
    int e = e0;
    for (; e + 2 <= e1; e += 2) {
      int s0 = wsrc[e];
      int s1 = wsrc[e + 1];
      union { _Float16 h[8]; uint4 u; } w0u, w1u;
      w0u.u = wts[e];
      w1u.u = wts[e + 1];
      float t0 = 0.f, t1 = 0.f;
      if (L1) {
        uint32 q0 = Q4[(size_t)s0 * 64 + lane];
        uint32 q1 = Q4[(size_t)s1 * 64 + lane];
        float sc0 = S[s0 * 8 + (lane >> 3)];
        float sc1 = S[s1 * 8 + (lane >> 3)];
        float v[8];
        dec8(q0, v);
#pragma unroll
        for (int j = 0; j < 8; j++) t0 += (float)w0u.h[j] * v[j];
        dec8(q1, v);
#pragma unroll
        for (int j = 0; j < 8; j++) t1 += (float)w1u.h[j] * v[j];
        t0 *= sc0;
        t1 *= sc1;
      } else {
        uint2 q0 = *(const uint2*)(Yq + (size_t)s0 * 512 + lane * 8);
        uint2 q1 = *(const uint2*)(Yq + (size_t)s1 * 512 + lane * 8);
        f32x2 a;
        a = __builtin_amdgcn_cvt_pk_f32_fp8((int)q0.x, false);
        t0 += (float)w0u.h[0] * a.x + (float)w0u.h[1] * a.y;
        a = __builtin_amdgcn_cvt_pk_f32_fp8((int)q0.x, true);
        t0 += (float)w0u.h[2] * a.x + (float)w0u.h[3] * a.y;
        a = __builtin_amdgcn_cvt_pk_f32_fp8((int)q0.y, false);
        t0 += (float)w0u.h[4] * a.x + (float)w0u.h[5] * a.y;
        a = __builtin_amdgcn_cvt_pk_f32_fp8((int)q0.y, true);
        t0 += (float)w0u.h[6] * a.x + (float)w0u.h[7] * a.y;
        a = __builtin_amdgcn_cvt_pk_f32_fp8((int)q1.x, false);
        t1 += (float)w1u.h[0] * a.x + (float)w1u.h[1] * a.y;
        a = __builtin_amdgcn_cvt_pk_f32_fp8((int)q1.x, true);
        t1 += (float)w1u.h[2] * a.x + (float)w1u.h[3] * a.y;
        a = __builtin_amdgcn_cvt_pk_f32_fp8((int)q1.y, false);
        t1 += (float)w1u.h[4] * a.x + (float)w1u.h[5] * a.y;
        a = __builtin_amdgcn_cvt_pk_f32_fp8((int)q1.y, true);
        t1 += (float)w1u.h[6] * a.x + (float)w1u.h[7] * a.y;
      }
      acc0 += t0;
      acc1 += t1;
    }
    if (e < e1) {
      int s0 = wsrc[e];
      union { _Float16 h[8]; uint4 u; } w0u;
      w0u.u = wts[e];
      float t0 = 0.f;
      if (L1) {
        uint32 q0 = Q4[(size_t)s0 * 64 + lane];
        float sc0 = S[s0 * 8 + (lane >> 3)];
        float v[8];
        dec8(q0, v);
#pragma unroll
        for (int j = 0; j < 8; j++) t0 += (float)w0u.h[j] * v[j];
        t0 *= sc0;
      } else {
        uint2 q0 = *(const uint2*)(Yq + (size_t)s0 * 512 + lane * 8);
        f32x2 a;
        a = __builtin_amdgcn_cvt_pk_f32_fp8((int)q0.x, false);
        t0 += (float)w0u.h[0] * a.x + (float)w0u.h[1] * a.y;
        a = __builtin_amdgcn_cvt_pk_f32_fp8((int)q0.x, true);
        t0 += (float)w0u.h[2] * a.x + (float)w0u.h[3] * a.y;
        a = __builtin_amdgcn_cvt_pk_f32_fp8((int)q0.y, false);
        t0 += (float)w0u.h[4] * a.x + (float)w0u.h[5] * a.y;
        a = __builtin_amdgcn_cvt_pk_f32_fp8((int)q0.y, true);
        t0 += (float)w0u.h[6] * a.x + (float)w0u.h[7] * a.y;
      }
      acc0 += t0;
    }
    float deg = (float)(e1 - e0);
    float inv = 1.f / fmaxf(deg, 1.f);
    float h = (acc0 + acc1) * inv +
              bf2f(((const unsigned short*)RS)[(size_t)n * RSS + lane]);
    ((unsigned short*)hout)[(size_t)n * 64 + lane] = f2bf(h);
    sh += h; sh2 += h * h;
    if (L1) {
      float s = bf2f(((const unsigned short*)RS)[(size_t)n * RSS + 64 + lane]);
      sout[(size_t)n * 64 + lane] = s;
      ss += s; ss2 += s * s;
    }
  }

  __shared__ float red[256];
  const int nst = L1 ? 4 : 2;
  float vals[4] = {sh, sh2, ss, ss2};
  for (int v = 0; v < nst; v++) {
    __syncthreads();
    red[tid] = vals[v];
    __syncthreads();
    if (tid < 64) {
      float tot = red[tid] + red[tid + 64] + red[tid + 128] + red[tid + 192];
      atomicAdd(&sums[v * 64 + tid], (double)tot);
    }
  }
}

// ---------------- bn finalize ----------------
__global__ void bn_finalize(const double* __restrict__ sums /*2x64*/, const float* __restrict__ g,
                            const float* __restrict__ b, float* __restrict__ scale,
                            float* __restrict__ shift, int N) {
  int t = threadIdx.x;
  if (t >= 64) return;
  double mean = sums[t] / (double)N;
  double var = sums[64 + t] / (double)N - mean * mean;
  double inv = 1.0 / sqrt(var + (double)BN_EPS);
  float sc = (float)((double)g[t] * inv);
  scale[t] = sc;
  shift[t] = b[t] - (float)mean * sc;
}

// ---------------- epilogue: out = elu(bn2(h2pre bf16) + bnS(spre)); spre lives in d_out -----
__global__ __launch_bounds__(256) void final_k(const __hip_bfloat16* __restrict__ h2pre,
                                               const float* __restrict__ scale2,
                                               const float* __restrict__ shift2,
                                               const float* __restrict__ scaleS,
                                               const float* __restrict__ shiftS,
                                               float* __restrict__ out, int total) {
  int idx = blockIdx.x * 256 + threadIdx.x;
  if (idx >= total) return;
  int ch = idx & 63;
  float h2 = bf2f(((const unsigned short*)h2pre)[idx]) * scale2[ch] + shift2[ch];
  float s = out[idx] * scaleS[ch] + shiftS[ch];
  float v = h2 + s;
  out[idx] = v > 0.f ? v : expm1f(v);
}

extern "C" void kernel_launch(void* const* d_in, const int* in_sizes, int n_in,
                              void* d_out, int out_size, void* d_ws, size_t ws_size,
                              hipStream_t stream) {
  const float* x     = (const float*)d_in[0];
  const int*   ei    = (const int*)d_in[1];
  const float* attr  = (const float*)d_in[2];
  const float* W1    = (const float*)d_in[3];
  const float* root1 = (const float*)d_in[4];
  const float* g1    = (const float*)d_in[5];
  const float* b1    = (const float*)d_in[6];
  const float* W2    = (const float*)d_in[7];
  const float* root2 = (const float*)d_in[8];
  const float* g2    = (const float*)d_in[9];
  const float* b2    = (const float*)d_in[10];
  const float* Wskip = (const float*)d_in[11];
  const float* gS    = (const float*)d_in[12];
  const float* bS    = (const float*)d_in[13];
  const int N = in_sizes[0] / 32;
  const int E = in_sizes[1] / 2;
  float* out = (float*)d_out;

  char* ws = (char*)d_ws;
  size_t off = 0;
  auto alloc = [&](size_t bytes) {
    void* p = ws + off;
    off = (off + bytes + 255) & ~(size_t)255;
    return p;
  };
  __hip_bfloat16* B1t = (__hip_bfloat16*)alloc(640 * 32 * 2);
  __hip_bfloat16* B2t = (__hip_bfloat16*)alloc(576 * 64 * 2);
  double* sums   = (double*)alloc(6 * 64 * 8);
  float*  scales = (float*)alloc(6 * 64 * 4);
  int*    indeg  = (int*)alloc((size_t)N * 4);
  int*    rowptr = (int*)alloc(((size_t)N + 1) * 4);
  int*    cursor = (int*)alloc((size_t)N * 4);
  int*    bsum   = (int*)alloc(1024 * 4);
  int*    wsrc   = (int*)alloc((size_t)E * 4);
  uint4*  wts    = (uint4*)alloc((size_t)E * 16);
  __hip_bfloat16* hagg = (__hip_bfloat16*)alloc((size_t)N * 64 * 2);  // hpre1 then h2pre, bf16
  unsigned char*  Yq = (unsigned char*)alloc((size_t)N * 512);        // fp8 table (L1 then L2)
  __hip_bfloat16* RS = (__hip_bfloat16*)alloc((size_t)N * 128 * 2);   // root(+skip) bf16
  uint32* Q4 = (uint32*)alloc((size_t)N * 256);                       // fp4 table (L1)
  float*  S  = (float*)alloc((size_t)N * 8 * 4);                      // per-64ch scales
  if (off > ws_size) return;  // workspace too small: fail gracefully

  hipMemsetAsync(indeg, 0, (size_t)N * 4, stream);
  hipMemsetAsync(sums, 0, 6 * 64 * 8, stream);

  pack_b1t<<<(640 * 32 + 255) / 256, 256, 0, stream>>>(W1, root1, Wskip, B1t);
  pack_b2t<<<(576 * 64 + 255) / 256, 256, 0, stream>>>(W2, root2, B2t);

  const int eblocks = (E + 255) / 256;
  const int nb = (N + 1023) / 1024;
  hist_dst<<<eblocks, 256, 0, stream>>>(ei, E, indeg);
  scan_block<<<nb, 1024, 0, stream>>>(indeg, cursor, bsum, N);
  scan_top<<<1, 1024, 0, stream>>>(bsum, nb);
  scan_add<<<(N + 255) / 256, 256, 0, stream>>>(cursor, bsum, rowptr, indeg, N, E);
  edge_scatter<<<eblocks, 256, 0, stream>>>(ei, attr, E, indeg, wsrc, wts);

  const int gblocks = (N + 63) / 64;

  // layer 1: [Yq|RS] = x @ [W1|root1|Wskip]; then fp4 requant
  gemm_mfma<32, false, true><<<gblocks, 256, 0, stream>>>(x, B1t, Yq, RS, N, 640, 128,
                                                          nullptr, nullptr);
  quant4<<<(N + 3) / 4, 256, 0, stream>>>(Yq, N, Q4, S);

  msg_dst<true><<<2048, 256, 0, stream>>>(Yq, Q4, S, RS, rowptr, wsrc, wts, N, hagg, out, sums);
  bn_finalize<<<1, 64, 0, stream>>>(sums + 0 * 64, g1, b1, scales + 0 * 64, scales + 1 * 64, N);
  bn_finalize<<<1, 64, 0, stream>>>(sums + 2 * 64, gS, bS, scales + 2 * 64, scales + 3 * 64, N);

  // layer 2: [Yq|RS] = elu(bn1(hagg)) @ [W2|root2]  (A is bf16)
  gemm_mfma<64, true, false><<<gblocks, 256, 0, stream>>>(hagg, B2t, Yq, RS, N, 576, 64,
                                                          scales + 0 * 64, scales + 1 * 64);

  msg_dst<false><<<2048, 256, 0, stream>>>(Yq, Q4, S, RS, rowptr, wsrc, wts, N, hagg, nullptr,
                                           sums + 4 * 64);
  bn_finalize<<<1, 64, 0, stream>>>(sums + 4 * 64, g2, b2, scales + 4 * 64, scales + 5 * 64, N);

  final_k<<<((N * 64) + 255) / 256, 256, 0, stream>>>(hagg, scales + 4 * 64, scales + 5 * 64,
                                                      scales + 2 * 64, scales + 3 * 64, out,
                                                      N * 64);
}

// Round 9
// 705.585 us; speedup vs baseline: 1.0175x; 1.0175x over previous
//
#include <hip/hip_runtime.h>
#include <hip/hip_bf16.h>
#include <cstdint>

#define BN_EPS 1e-5f

typedef __attribute__((ext_vector_type(8))) short bf16x8;
typedef __attribute__((ext_vector_type(4))) float f32x4;
typedef __attribute__((ext_vector_type(2))) float f32x2;
typedef unsigned int uint32;

__device__ inline unsigned short f2bf(float f) {
  unsigned int b = __float_as_uint(f);
  b += 0x7FFFu + ((b >> 16) & 1u);  // RNE
  return (unsigned short)(b >> 16);
}
__device__ inline float bf2f(unsigned short u) { return __uint_as_float((unsigned int)u << 16); }
__device__ inline unsigned char f2fp8(float f) {
  int p = __builtin_amdgcn_cvt_pk_fp8_f32(f, f, 0, false);  // OCP e4m3 on gfx950
  return (unsigned char)(p & 0xFF);
}

// ---------------- pack weights (both layers, one launch): bf16 [Ncols][K] ----------------
__global__ void pack_bt(const float* __restrict__ W1, const float* __restrict__ root1,
                        const float* __restrict__ Wskip, const float* __restrict__ W2,
                        const float* __restrict__ root2, __hip_bfloat16* __restrict__ B1t,
                        __hip_bfloat16* __restrict__ B2t) {
  int idx = blockIdx.x * blockDim.x + threadIdx.x;
  if (idx < 640 * 32) {
    int n = idx >> 5, k = idx & 31;
    float v;
    if (n < 512) v = W1[(n & 7) * (32 * 64) + k * 64 + (n >> 3)];
    else if (n < 576) v = root1[k * 64 + (n - 512)];
    else v = Wskip[k * 64 + (n - 576)];
    ((unsigned short*)B1t)[idx] = f2bf(v);
  }
  int idx2 = idx - 640 * 32;
  if (idx2 >= 0 && idx2 < 576 * 64) {
    int n = idx2 >> 6, k = idx2 & 63;
    float v;
    if (n < 512) v = W2[(n & 7) * (64 * 64) + k * 64 + (n >> 3)];
    else v = root2[k * 64 + (n - 512)];
    ((unsigned short*)B2t)[idx2] = f2bf(v);
  }
}

// ---------------- dst-CSR build ----------------
__global__ void hist_dst(const int* __restrict__ ei, int E, int* __restrict__ indeg) {
  int e = blockIdx.x * 256 + threadIdx.x;
  if (e >= E) return;
  atomicAdd(&indeg[ei[E + e]], 1);
}

__global__ __launch_bounds__(1024) void scan_block(const int* __restrict__ in,
                                                   int* __restrict__ part,
                                                   int* __restrict__ bsum, int N) {
  __shared__ int tmp[1024];
  int i = blockIdx.x * 1024 + threadIdx.x;
  int v = (i < N) ? in[i] : 0;
  tmp[threadIdx.x] = v;
  __syncthreads();
  for (int ofs = 1; ofs < 1024; ofs <<= 1) {
    int t = (threadIdx.x >= (unsigned)ofs) ? tmp[threadIdx.x - ofs] : 0;
    __syncthreads();
    tmp[threadIdx.x] += t;
    __syncthreads();
  }
  if (i < N) part[i] = tmp[threadIdx.x] - v;
  if (threadIdx.x == 1023) bsum[blockIdx.x] = tmp[1023];
}

__global__ __launch_bounds__(1024) void scan_top(int* __restrict__ bsum, int nb) {
  __shared__ int tmp[1024];
  int v = (threadIdx.x < (unsigned)nb) ? bsum[threadIdx.x] : 0;
  tmp[threadIdx.x] = v;
  __syncthreads();
  for (int ofs = 1; ofs < 1024; ofs <<= 1) {
    int t = (threadIdx.x >= (unsigned)ofs) ? tmp[threadIdx.x - ofs] : 0;
    __syncthreads();
    tmp[threadIdx.x] += t;
    __syncthreads();
  }
  if (threadIdx.x < (unsigned)nb) bsum[threadIdx.x] = tmp[threadIdx.x] - v;
}

__global__ void scan_add(const int* __restrict__ part, const int* __restrict__ bsum,
                         int* __restrict__ rowptr, int* __restrict__ cursor, int N, int E) {
  int i = blockIdx.x * 256 + threadIdx.x;
  if (i < N) {
    int r = part[i] + bsum[i >> 10];
    rowptr[i] = r;
    cursor[i] = r;
  }
  if (i == 0) rowptr[N] = E;
}

// Scatter: ONE 32-B slot per edge: {src, pad, 8x fp16 weights} -> single random line touch.
__global__ void edge_scatter(const int* __restrict__ ei, const float* __restrict__ attr, int E,
                             int* __restrict__ cursor, uint4* __restrict__ emeta) {
  int e = blockIdx.x * 256 + threadIdx.x;
  if (e >= E) return;
  int src = ei[e], dst = ei[E + e];
  float u0 = attr[3 * e + 0], u1 = attr[3 * e + 1], u2 = attr[3 * e + 2];
  float p0 = 1.f - u0, p1 = 1.f - u1, p2 = 1.f - u2;
  float w00 = p1 * p2, w10 = u1 * p2, w01 = p1 * u2, w11 = u1 * u2;
  float w[8] = {p0 * w00, u0 * w00, p0 * w10, u0 * w10,
                p0 * w01, u0 * w01, p0 * w11, u0 * w11};
  union { _Float16 h[8]; uint32 u[4]; } pk;
#pragma unroll
  for (int j = 0; j < 8; j++) pk.h[j] = (_Float16)w[j];
  int pos = atomicAdd(&cursor[dst], 1);
  emeta[2 * (size_t)pos + 0] = make_uint4((uint32)src, 0u, pk.u[0], pk.u[1]);
  emeta[2 * (size_t)pos + 1] = make_uint4(pk.u[2], pk.u[3], 0u, 0u);
}

// ---------------- MFMA GEMM: [Yq fp8 (cols 0..511) | RS bf16 (cols 512+)] = A @ Bt^T ----------
// AF32: A fp32 (layer 1) or bf16 (layer 2). BN applies scale/shift+ELU to A.
template <int K, bool BN, bool AF32>
__global__ __launch_bounds__(256) void gemm_mfma(const void* __restrict__ Av,
                                                 const __hip_bfloat16* __restrict__ Bt,
                                                 unsigned char* __restrict__ Yq,
                                                 __hip_bfloat16* __restrict__ RS, int M,
                                                 int Ncols, int rss,
                                                 const float* __restrict__ scale,
                                                 const float* __restrict__ shift) {
  const int tid = threadIdx.x;
  const int lane = tid & 63;
  const int wv = tid >> 6;
  const int rowbase = blockIdx.x * 64 + wv * 16;
  const int m = lane & 15;
  const int quad = lane >> 4;
  const int k0 = quad * 8;

  int ar = rowbase + m;
  if (ar > M - 1) ar = M - 1;

  bf16x8 afrag[K / 32];
#pragma unroll
  for (int f = 0; f < K / 32; f++) {
    float v[8];
#pragma unroll
    for (int j = 0; j < 8; j++) {
      if (AF32) v[j] = ((const float*)Av)[(size_t)ar * K + f * 32 + k0 + j];
      else v[j] = bf2f(((const unsigned short*)Av)[(size_t)ar * K + f * 32 + k0 + j]);
    }
    if (BN) {
#pragma unroll
      for (int j = 0; j < 8; j++) {
        float t = v[j] * scale[f * 32 + k0 + j] + shift[f * 32 + k0 + j];
        v[j] = t > 0.f ? t : expm1f(t);
      }
    }
    bf16x8 af;
#pragma unroll
    for (int j = 0; j < 8; j++) af[j] = (short)f2bf(v[j]);
    afrag[f] = af;
  }

  for (int col0 = 0; col0 < Ncols; col0 += 16) {
    f32x4 acc = {0.f, 0.f, 0.f, 0.f};
#pragma unroll
    for (int f = 0; f < K / 32; f++) {
      const __hip_bfloat16* bp = Bt + (size_t)(col0 + m) * K + f * 32 + k0;
      bf16x8 bfrag = *(const bf16x8*)bp;
      acc = __builtin_amdgcn_mfma_f32_16x16x32_bf16(afrag[f], bfrag, acc, 0, 0, 0);
    }
    const int col = col0 + m;
#pragma unroll
    for (int r = 0; r < 4; r++) {
      int gr = rowbase + quad * 4 + r;
      if (gr < M) {
        if (col < 512) Yq[(size_t)gr * 512 + col] = f2fp8(acc[r]);
        else ((unsigned short*)RS)[(size_t)gr * rss + (col - 512)] = f2bf(acc[r]);
      }
    }
  }
}

// ---------------- dst-grouped message + finish: one wave per dst node ----------------
// Gathers fp8 Yq rows; scalar emeta; writes hout bf16; per-channel BN stats.
// L1 additionally computes skip stats from RS (cols 64..127) but does NOT copy them.
template <bool L1>
__global__ __launch_bounds__(256) void msg_dst(const unsigned char* __restrict__ Yq,
                                               const __hip_bfloat16* __restrict__ RS,
                                               const int* __restrict__ rowptr,
                                               const uint4* __restrict__ emeta, int N,
                                               __hip_bfloat16* __restrict__ hout,
                                               double* __restrict__ sums) {
  const int tid = threadIdx.x;
  const int lane = tid & 63;
  const int wv = tid >> 6;
  const int nwaves = gridDim.x * 4;
  const int lo8 = lane * 8;
  const int RSS = L1 ? 128 : 64;
  float sh = 0.f, sh2 = 0.f, ss = 0.f, ss2 = 0.f;

  for (int n = blockIdx.x * 4 + wv; n < N; n += nwaves) {
    const int e0 = __builtin_amdgcn_readfirstlane(rowptr[n]);
    const int e1 = __builtin_amdgcn_readfirstlane(rowptr[n + 1]);
    float acc0 = 0.f, acc1 = 0.f;
    int e = e0;
    for (; e + 2 <= e1; e += 2) {
      uint4 m00 = emeta[2 * (size_t)e + 0];
      uint4 m01 = emeta[2 * (size_t)e + 1];
      uint4 m10 = emeta[2 * (size_t)e + 2];
      uint4 m11 = emeta[2 * (size_t)e + 3];
      int s0 = (int)m00.x;
      int s1 = (int)m10.x;
      union { uint32 u[4]; _Float16 h[8]; } w0u, w1u;
      w0u.u[0] = m00.z; w0u.u[1] = m00.w; w0u.u[2] = m01.x; w0u.u[3] = m01.y;
      w1u.u[0] = m10.z; w1u.u[1] = m10.w; w1u.u[2] = m11.x; w1u.u[3] = m11.y;
      uint2 q0 = *(const uint2*)(Yq + (size_t)s0 * 512 + lo8);
      uint2 q1 = *(const uint2*)(Yq + (size_t)s1 * 512 + lo8);
      float t0 = 0.f, t1 = 0.f;
      f32x2 a;
      a = __builtin_amdgcn_cvt_pk_f32_fp8((int)q0.x, false);
      t0 += (float)w0u.h[0] * a.x + (float)w0u.h[1] * a.y;
      a = __builtin_amdgcn_cvt_pk_f32_fp8((int)q0.x, true);
      t0 += (float)w0u.h[2] * a.x + (float)w0u.h[3] * a.y;
      a = __builtin_amdgcn_cvt_pk_f32_fp8((int)q0.y, false);
      t0 += (float)w0u.h[4] * a.x + (float)w0u.h[5] * a.y;
      a = __builtin_amdgcn_cvt_pk_f32_fp8((int)q0.y, true);
      t0 += (float)w0u.h[6] * a.x + (float)w0u.h[7] * a.y;
      a = __builtin_amdgcn_cvt_pk_f32_fp8((int)q1.x, false);
      t1 += (float)w1u.h[0] * a.x + (float)w1u.h[1] * a.y;
      a = __builtin_amdgcn_cvt_pk_f32_fp8((int)q1.x, true);
      t1 += (float)w1u.h[2] * a.x + (float)w1u.h[3] * a.y;
      a = __builtin_amdgcn_cvt_pk_f32_fp8((int)q1.y, false);
      t1 += (float)w1u.h[4] * a.x + (float)w1u.h[5] * a.y;
      a = __builtin_amdgcn_cvt_pk_f32_fp8((int)q1.y, true);
      t1 += (float)w1u.h[6] * a.x + (float)w1u.h[7] * a.y;
      acc0 += t0;
      acc1 += t1;
    }
    if (e < e1) {
      uint4 m00 = emeta[2 * (size_t)e + 0];
      uint4 m01 = emeta[2 * (size_t)e + 1];
      int s0 = (int)m00.x;
      union { uint32 u[4]; _Float16 h[8]; } w0u;
      w0u.u[0] = m00.z; w0u.u[1] = m00.w; w0u.u[2] = m01.x; w0u.u[3] = m01.y;
      uint2 q0 = *(const uint2*)(Yq + (size_t)s0 * 512 + lo8);
      float t0 = 0.f;
      f32x2 a;
      a = __builtin_amdgcn_cvt_pk_f32_fp8((int)q0.x, false);
      t0 += (float)w0u.h[0] * a.x + (float)w0u.h[1] * a.y;
      a = __builtin_amdgcn_cvt_pk_f32_fp8((int)q0.x, true);
      t0 += (float)w0u.h[2] * a.x + (float)w0u.h[3] * a.y;
      a = __builtin_amdgcn_cvt_pk_f32_fp8((int)q0.y, false);
      t0 += (float)w0u.h[4] * a.x + (float)w0u.h[5] * a.y;
      a = __builtin_amdgcn_cvt_pk_f32_fp8((int)q0.y, true);
      t0 += (float)w0u.h[6] * a.x + (float)w0u.h[7] * a.y;
      acc0 += t0;
    }
    float deg = (float)(e1 - e0);
    float inv = 1.f / fmaxf(deg, 1.f);
    float h = (acc0 + acc1) * inv +
              bf2f(((const unsigned short*)RS)[(size_t)n * RSS + lane]);
    ((unsigned short*)hout)[(size_t)n * 64 + lane] = f2bf(h);
    sh += h; sh2 += h * h;
    if (L1) {
      float s = bf2f(((const unsigned short*)RS)[(size_t)n * RSS + 64 + lane]);
      ss += s; ss2 += s * s;
    }
  }

  __shared__ float red[256];
  const int nst = L1 ? 4 : 2;
  float vals[4] = {sh, sh2, ss, ss2};
  for (int v = 0; v < nst; v++) {
    __syncthreads();
    red[tid] = vals[v];
    __syncthreads();
    if (tid < 64) {
      float tot = red[tid] + red[tid + 64] + red[tid + 128] + red[tid + 192];
      atomicAdd(&sums[v * 64 + tid], (double)tot);
    }
  }
}

// ---------------- bn finalize: one or two parameter sets per launch ----------------
__global__ void bn_finalize2(const double* __restrict__ sums, const float* __restrict__ gA,
                             const float* __restrict__ bA, const float* __restrict__ gB,
                             const float* __restrict__ bB, float* __restrict__ scales, int N) {
  int t = threadIdx.x;  // 0..127 (or 0..63 if gB==nullptr)
  int set = t >> 6, ch = t & 63;
  if (set == 1 && gB == nullptr) return;
  const float* g = set ? gB : gA;
  const float* b = set ? bB : bA;
  double mean = sums[set * 128 + ch] / (double)N;
  double var = sums[set * 128 + 64 + ch] / (double)N - mean * mean;
  double inv = 1.0 / sqrt(var + (double)BN_EPS);
  float sc = (float)((double)g[ch] * inv);
  scales[set * 128 + ch] = sc;
  scales[set * 128 + 64 + ch] = b[ch] - (float)mean * sc;
}

// ---------------- epilogue: out = elu(bn2(h2pre) + bnS(skip from RS1)) ----------------
__global__ __launch_bounds__(256) void final_k(const __hip_bfloat16* __restrict__ h2pre,
                                               const __hip_bfloat16* __restrict__ RS1,
                                               const float* __restrict__ sc2,   // [scale|shift]
                                               const float* __restrict__ scS,
                                               float* __restrict__ out, int total) {
  int idx = blockIdx.x * 256 + threadIdx.x;
  if (idx >= total) return;
  int ch = idx & 63;
  int n = idx >> 6;
  float h2 = bf2f(((const unsigned short*)h2pre)[idx]) * sc2[ch] + sc2[64 + ch];
  float s = bf2f(((const unsigned short*)RS1)[(size_t)n * 128 + 64 + ch]) * scS[ch] + scS[64 + ch];
  float v = h2 + s;
  out[idx] = v > 0.f ? v : expm1f(v);
}

extern "C" void kernel_launch(void* const* d_in, const int* in_sizes, int n_in,
                              void* d_out, int out_size, void* d_ws, size_t ws_size,
                              hipStream_t stream) {
  const float* x     = (const float*)d_in[0];
  const int*   ei    = (const int*)d_in[1];
  const float* attr  = (const float*)d_in[2];
  const float* W1    = (const float*)d_in[3];
  const float* root1 = (const float*)d_in[4];
  const float* g1    = (const float*)d_in[5];
  const float* b1    = (const float*)d_in[6];
  const float* W2    = (const float*)d_in[7];
  const float* root2 = (const float*)d_in[8];
  const float* g2    = (const float*)d_in[9];
  const float* b2    = (const float*)d_in[10];
  const float* Wskip = (const float*)d_in[11];
  const float* gS    = (const float*)d_in[12];
  const float* bS    = (const float*)d_in[13];
  const int N = in_sizes[0] / 32;
  const int E = in_sizes[1] / 2;
  float* out = (float*)d_out;

  char* ws = (char*)d_ws;
  size_t off = 0;
  auto alloc = [&](size_t bytes) {
    void* p = ws + off;
    off = (off + bytes + 255) & ~(size_t)255;
    return p;
  };
  __hip_bfloat16* B1t = (__hip_bfloat16*)alloc(640 * 32 * 2);
  __hip_bfloat16* B2t = (__hip_bfloat16*)alloc(576 * 64 * 2);
  double* sums   = (double*)alloc(6 * 64 * 8);   // [h1 mean,sq | skip mean,sq | h2 mean,sq]
  float*  scales = (float*)alloc(6 * 64 * 4);    // [bn1 sc,sh | bnS sc,sh | bn2 sc,sh]
  int*    indeg  = (int*)alloc((size_t)N * 4);
  int*    rowptr = (int*)alloc(((size_t)N + 1) * 4);
  int*    cursor = (int*)alloc((size_t)N * 4);
  int*    bsum   = (int*)alloc(1024 * 4);
  uint4*  emeta  = (uint4*)alloc((size_t)E * 32);                     // {src,pad,w8xfp16}
  __hip_bfloat16* hagg = (__hip_bfloat16*)alloc((size_t)N * 64 * 2);  // hpre1 then h2pre
  unsigned char*  Yq  = (unsigned char*)alloc((size_t)N * 512);       // fp8 gather table
  __hip_bfloat16* RS1 = (__hip_bfloat16*)alloc((size_t)N * 128 * 2);  // L1 root|skip
  __hip_bfloat16* RS2 = (__hip_bfloat16*)alloc((size_t)N * 64 * 2);   // L2 root
  if (off > ws_size) return;  // workspace too small: fail gracefully

  hipMemsetAsync(indeg, 0, (size_t)N * 4, stream);
  hipMemsetAsync(sums, 0, 6 * 64 * 8, stream);

  pack_bt<<<(640 * 32 + 576 * 64 + 255) / 256, 256, 0, stream>>>(W1, root1, Wskip, W2, root2,
                                                                 B1t, B2t);

  const int eblocks = (E + 255) / 256;
  const int nb = (N + 1023) / 1024;
  hist_dst<<<eblocks, 256, 0, stream>>>(ei, E, indeg);
  scan_block<<<nb, 1024, 0, stream>>>(indeg, cursor, bsum, N);
  scan_top<<<1, 1024, 0, stream>>>(bsum, nb);
  scan_add<<<(N + 255) / 256, 256, 0, stream>>>(cursor, bsum, rowptr, indeg, N, E);
  edge_scatter<<<eblocks, 256, 0, stream>>>(ei, attr, E, indeg, emeta);

  const int gblocks = (N + 63) / 64;

  // layer 1: [Yq|RS1] = x @ [W1|root1|Wskip]
  gemm_mfma<32, false, true><<<gblocks, 256, 0, stream>>>(x, B1t, Yq, RS1, N, 640, 128,
                                                          nullptr, nullptr);

  msg_dst<true><<<2048, 256, 0, stream>>>(Yq, RS1, rowptr, emeta, N, hagg, sums);
  bn_finalize2<<<1, 128, 0, stream>>>(sums, g1, b1, gS, bS, scales, N);  // bn1 + bnS

  // layer 2: [Yq|RS2] = elu(bn1(hagg)) @ [W2|root2]  (A bf16)
  gemm_mfma<64, true, false><<<gblocks, 256, 0, stream>>>(hagg, B2t, Yq, RS2, N, 576, 64,
                                                          scales + 0 * 64, scales + 1 * 64);

  msg_dst<false><<<2048, 256, 0, stream>>>(Yq, RS2, rowptr, emeta, N, hagg, sums + 4 * 64);
  bn_finalize2<<<1, 64, 0, stream>>>(sums + 4 * 64, g2, b2, nullptr, nullptr,
                                     scales + 4 * 64, N);

  final_k<<<((N * 64) + 255) / 256, 256, 0, stream>>>(hagg, RS1, scales + 4 * 64,
                                                      scales + 2 * 64, out, N * 64);
}